// Round 1
// baseline (270.908 us; speedup 1.0000x reference)
//
#include <hip/hip_runtime.h>

#define TT 2048
#define NB 16
#define FD 128
#define ALPHA 0.2f

typedef __attribute__((ext_vector_type(8))) short short8;
typedef __attribute__((ext_vector_type(4))) float f32x4;

static __device__ __forceinline__ unsigned short f2bf(float f) {
    unsigned u = __float_as_uint(f);
    u += 0x7FFF + ((u >> 16) & 1);          // round-to-nearest-even
    return (unsigned short)(u >> 16);
}
static __device__ __forceinline__ float bf2f(unsigned short s) {
    return __uint_as_float(((unsigned)s) << 16);
}

// Kernel 1: h = x@W (bf16 MFMA), write hT[b][f][t] bf16, s1 = h@a1, s2 = h@a2 (fp32)
__global__ __launch_bounds__(256) void k_h(const float* __restrict__ x,
                                           const float* __restrict__ W,
                                           const float* __restrict__ a,
                                           unsigned short* __restrict__ hT,
                                           float* __restrict__ s1,
                                           float* __restrict__ s2)
{
    __shared__ unsigned short WT[128][136];  // W^T bf16, padded (2-way-free reads)
    __shared__ unsigned short hs[128][72];   // h-tile transpose staging

    const int tid = threadIdx.x;
    const int b  = blockIdx.x >> 5;
    const int t0 = (blockIdx.x & 31) << 6;

    // stage W^T into LDS as bf16 (coalesced float4 reads)
    for (int it = 0; it < 16; ++it) {
        int fid = it * 256 + tid;            // 4096 float4s
        int k = fid >> 5;
        int f = (fid & 31) << 2;
        float4 w4 = *reinterpret_cast<const float4*>(W + k * FD + f);
        WT[f + 0][k] = f2bf(w4.x);
        WT[f + 1][k] = f2bf(w4.y);
        WT[f + 2][k] = f2bf(w4.z);
        WT[f + 3][k] = f2bf(w4.w);
    }
    __syncthreads();

    const int w = tid >> 6, l = tid & 63, g = l >> 4, r15 = l & 15;
    const float* xrow = x + ((size_t)(b * TT + t0 + w * 16 + r15)) * FD;

    f32x4 acc[8] = {};

    #pragma unroll
    for (int m = 0; m < 4; ++m) {
        const int koff = m * 32 + g * 8;
        float4 xa = *reinterpret_cast<const float4*>(xrow + koff);
        float4 xb = *reinterpret_cast<const float4*>(xrow + koff + 4);
        short8 af;
        af[0] = (short)f2bf(xa.x); af[1] = (short)f2bf(xa.y);
        af[2] = (short)f2bf(xa.z); af[3] = (short)f2bf(xa.w);
        af[4] = (short)f2bf(xb.x); af[5] = (short)f2bf(xb.y);
        af[6] = (short)f2bf(xb.z); af[7] = (short)f2bf(xb.w);
        #pragma unroll
        for (int n = 0; n < 8; ++n) {
            short8 bfr = *reinterpret_cast<const short8*>(&WT[n * 16 + r15][koff]);
            acc[n] = __builtin_amdgcn_mfma_f32_16x16x32_bf16(af, bfr, acc[n], 0, 0, 0);
        }
    }

    // s1/s2 from fp32 accumulators: lane holds h[t0+w*16+4g+r][16n+r15]
    float p1[4] = {0.f, 0.f, 0.f, 0.f}, p2[4] = {0.f, 0.f, 0.f, 0.f};
    #pragma unroll
    for (int n = 0; n < 8; ++n) {
        float a1v = a[n * 16 + r15];
        float a2v = a[FD + n * 16 + r15];
        #pragma unroll
        for (int r = 0; r < 4; ++r) {
            p1[r] += acc[n][r] * a1v;
            p2[r] += acc[n][r] * a2v;
        }
    }
    #pragma unroll
    for (int r = 0; r < 4; ++r) {
        #pragma unroll
        for (int off = 8; off >= 1; off >>= 1) {
            p1[r] += __shfl_xor(p1[r], off);
            p2[r] += __shfl_xor(p2[r], off);
        }
    }
    if (r15 == 0) {
        const int trow = t0 + w * 16 + g * 4;
        #pragma unroll
        for (int r = 0; r < 4; ++r) {
            s1[b * TT + trow + r] = p1[r];
            s2[b * TT + trow + r] = p2[r];
        }
    }

    // transpose h tile through LDS, write hT[b][f][t] coalesced
    #pragma unroll
    for (int n = 0; n < 8; ++n)
        #pragma unroll
        for (int r = 0; r < 4; ++r)
            hs[n * 16 + r15][w * 16 + g * 4 + r] = f2bf(acc[n][r]);
    __syncthreads();

    for (int i = tid; i < 1024; i += 256) {
        int f = i >> 3, c = i & 7;
        short8 v = *reinterpret_cast<const short8*>(&hs[f][c * 8]);
        *reinterpret_cast<short8*>(hT + ((size_t)(b * FD + f)) * TT + t0 + c * 8) = v;
    }
}

// Kernel 2: flash-style fused mask+softmax+PV. One block = 64 i-rows, 4 waves.
// No barriers in the j-loop; adj read directly from global in A-fragment layout.
__global__ __launch_bounds__(256) void k_att(const int* __restrict__ adj,
                                             const unsigned short* __restrict__ hT,
                                             const float* __restrict__ s1,
                                             const float* __restrict__ s2,
                                             float* __restrict__ out)
{
    __shared__ float lsm[64];
    const int tid = threadIdx.x;
    const int b  = blockIdx.x >> 5;
    const int i0 = (blockIdx.x & 31) << 6;
    const int w = tid >> 6, l = tid & 63, g = l >> 4, r15 = l & 15;

    const int arow = i0 + w * 16 + r15;                 // A-fragment row (i)
    const float s1v = s1[b * TT + arow];
    const int* adjp = adj + ((size_t)b * TT + arow) * TT;
    const unsigned short* hTb = hT + (size_t)b * FD * TT + (size_t)r15 * TT;
    const float* s2b = s2 + b * TT;

    f32x4 acc[8] = {};
    float lsum = 0.f;

    for (int j0 = 0; j0 < TT; j0 += 64) {
        #pragma unroll
        for (int m = 0; m < 2; ++m) {
            const int koff = j0 + m * 32 + g * 8;
            int4 A0 = *reinterpret_cast<const int4*>(adjp + koff);
            int4 A1 = *reinterpret_cast<const int4*>(adjp + koff + 4);
            float4 S0 = *reinterpret_cast<const float4*>(s2b + koff);
            float4 S1 = *reinterpret_cast<const float4*>(s2b + koff + 4);
            int   ad[8] = {A0.x, A0.y, A0.z, A0.w, A1.x, A1.y, A1.z, A1.w};
            float sv[8] = {S0.x, S0.y, S0.z, S0.w, S1.x, S1.y, S1.z, S1.w};
            short8 af;
            #pragma unroll
            for (int e = 0; e < 8; ++e) {
                float s = s1v + sv[e];
                s = fmaxf(s, 0.f) + ALPHA * fminf(s, 0.f);   // leaky_relu
                float p = ad[e] ? __expf(s) : 0.f;           // mask -> exp(-1e9)=0
                unsigned short u = f2bf(p);
                af[e] = (short)u;
                lsum += bf2f(u);      // denominator from the SAME rounded weights
            }
            #pragma unroll
            for (int n = 0; n < 8; ++n) {
                short8 bfr = *reinterpret_cast<const short8*>(hTb + n * 16 * TT + koff);
                acc[n] = __builtin_amdgcn_mfma_f32_16x16x32_bf16(af, bfr, acc[n], 0, 0, 0);
            }
        }
    }

    // row sums: lane's lsum is a partial for row r15; reduce over k-groups
    lsum += __shfl_xor(lsum, 16);
    lsum += __shfl_xor(lsum, 32);
    if (g == 0) lsm[w * 16 + r15] = lsum;
    __syncthreads();

    float rin[4];
    #pragma unroll
    for (int r = 0; r < 4; ++r) rin[r] = 1.0f / lsm[w * 16 + g * 4 + r];

    const int orow0 = b * TT + i0 + w * 16 + g * 4;     // C rows = 4g + r
    #pragma unroll
    for (int r = 0; r < 4; ++r) {
        float* orow = out + (size_t)(orow0 + r) * FD + r15;
        #pragma unroll
        for (int n = 0; n < 8; ++n)
            orow[n * 16] = acc[n][r] * rin[r];
    }
}

extern "C" void kernel_launch(void* const* d_in, const int* in_sizes, int n_in,
                              void* d_out, int out_size, void* d_ws, size_t ws_size,
                              hipStream_t stream)
{
    const float* x  = (const float*)d_in[0];
    const int* adj  = (const int*)d_in[1];
    const float* W  = (const float*)d_in[2];
    const float* a  = (const float*)d_in[3];
    float* out = (float*)d_out;

    unsigned short* hT = (unsigned short*)d_ws;                       // 8 MB bf16
    float* s1 = (float*)((char*)d_ws + (size_t)NB * FD * TT * 2);
    float* s2 = s1 + NB * TT;

    k_h  <<<NB * (TT / 64), 256, 0, stream>>>(x, W, a, hT, s1, s2);
    k_att<<<NB * (TT / 64), 256, 0, stream>>>(adj, hT, s1, s2, out);
}

// Round 2
// 220.028 us; speedup vs baseline: 1.2312x; 1.2312x over previous
//
#include <hip/hip_runtime.h>

#define TT 2048
#define NB 16
#define FD 128
#define ALPHA 0.2f

typedef __attribute__((ext_vector_type(8))) short short8;
typedef __attribute__((ext_vector_type(4))) float f32x4;

static __device__ __forceinline__ unsigned short f2bf(float f) {
    unsigned u = __float_as_uint(f);
    u += 0x7FFF + ((u >> 16) & 1);          // round-to-nearest-even
    return (unsigned short)(u >> 16);
}
static __device__ __forceinline__ float bf2f(unsigned short s) {
    return __uint_as_float(((unsigned)s) << 16);
}

// Kernel 0: WT[f][k] = bf16(W[k][f])  (128x128, tiny)
__global__ __launch_bounds__(256) void k_wt(const float* __restrict__ W,
                                            unsigned short* __restrict__ WT)
{
    int fid = blockIdx.x * 256 + threadIdx.x;   // 4096 float4s
    int k = fid >> 5;
    int f = (fid & 31) << 2;
    float4 w4 = *reinterpret_cast<const float4*>(W + k * FD + f);
    WT[(f + 0) * FD + k] = f2bf(w4.x);
    WT[(f + 1) * FD + k] = f2bf(w4.y);
    WT[(f + 2) * FD + k] = f2bf(w4.z);
    WT[(f + 3) * FD + k] = f2bf(w4.w);
}

// Kernel 1: h = x@W (bf16 MFMA, WT from L2), write hT[b][f][t] bf16,
//           s1 = h@a1, s2 = h@a2 (fp32)
__global__ __launch_bounds__(256) void k_h(const float* __restrict__ x,
                                           const unsigned short* __restrict__ WT,
                                           const float* __restrict__ a,
                                           unsigned short* __restrict__ hT,
                                           float* __restrict__ s1,
                                           float* __restrict__ s2)
{
    __shared__ unsigned short hs[128][72];   // h-tile transpose staging

    const int tid = threadIdx.x;
    const int b  = blockIdx.x >> 5;
    const int t0 = (blockIdx.x & 31) << 6;
    const int w = tid >> 6, l = tid & 63, g = l >> 4, r15 = l & 15;

    const float* xrow = x + ((size_t)(b * TT + t0 + w * 16 + r15)) * FD;

    f32x4 acc[8] = {};

    #pragma unroll
    for (int m = 0; m < 4; ++m) {
        const int koff = m * 32 + g * 8;
        float4 xa = *reinterpret_cast<const float4*>(xrow + koff);
        float4 xb = *reinterpret_cast<const float4*>(xrow + koff + 4);
        short8 af;
        af[0] = (short)f2bf(xa.x); af[1] = (short)f2bf(xa.y);
        af[2] = (short)f2bf(xa.z); af[3] = (short)f2bf(xa.w);
        af[4] = (short)f2bf(xb.x); af[5] = (short)f2bf(xb.y);
        af[6] = (short)f2bf(xb.z); af[7] = (short)f2bf(xb.w);
        #pragma unroll
        for (int n = 0; n < 8; ++n) {
            short8 bfr = *reinterpret_cast<const short8*>(WT + (n * 16 + r15) * FD + koff);
            acc[n] = __builtin_amdgcn_mfma_f32_16x16x32_bf16(af, bfr, acc[n], 0, 0, 0);
        }
    }

    // s1/s2 from fp32 accumulators: lane holds h[t0+w*16+4g+r][16n+r15]
    float p1[4] = {0.f, 0.f, 0.f, 0.f}, p2[4] = {0.f, 0.f, 0.f, 0.f};
    #pragma unroll
    for (int n = 0; n < 8; ++n) {
        float a1v = a[n * 16 + r15];
        float a2v = a[FD + n * 16 + r15];
        #pragma unroll
        for (int r = 0; r < 4; ++r) {
            p1[r] += acc[n][r] * a1v;
            p2[r] += acc[n][r] * a2v;
        }
    }
    #pragma unroll
    for (int r = 0; r < 4; ++r) {
        #pragma unroll
        for (int off = 8; off >= 1; off >>= 1) {
            p1[r] += __shfl_xor(p1[r], off);
            p2[r] += __shfl_xor(p2[r], off);
        }
    }
    if (r15 == 0) {
        const int trow = t0 + w * 16 + g * 4;
        #pragma unroll
        for (int r = 0; r < 4; ++r) {
            s1[b * TT + trow + r] = p1[r];
            s2[b * TT + trow + r] = p2[r];
        }
    }

    // transpose h tile through LDS, write hT[b][f][t] coalesced
    #pragma unroll
    for (int n = 0; n < 8; ++n)
        #pragma unroll
        for (int r = 0; r < 4; ++r)
            hs[n * 16 + r15][w * 16 + g * 4 + r] = f2bf(acc[n][r]);
    __syncthreads();

    for (int i = tid; i < 1024; i += 256) {
        int f = i >> 3, c = i & 7;
        short8 v = *reinterpret_cast<const short8*>(&hs[f][c * 8]);
        *reinterpret_cast<short8*>(hT + ((size_t)(b * FD + f)) * TT + t0 + c * 8) = v;
    }
}

// Kernel 2: fused mask+softmax+PV. One block = 16 i-rows, 4 waves each owning
// a 512-wide j-chunk (partial sums are additive in unstable softmax), LDS
// two-step reduction. 2048 blocks -> full occupancy.
__global__ __launch_bounds__(256) void k_att(const int* __restrict__ adj,
                                             const unsigned short* __restrict__ hT,
                                             const float* __restrict__ s1,
                                             const float* __restrict__ s2,
                                             float* __restrict__ out)
{
    __shared__ __align__(16) float red[2][16][132];
    __shared__ float dsum[4][16];

    const int tid = threadIdx.x;
    const int b  = blockIdx.x >> 7;
    const int i0 = (blockIdx.x & 127) << 4;
    const int w = tid >> 6, l = tid & 63, g = l >> 4, r15 = l & 15;

    const int arow = i0 + r15;                          // A-fragment row (i)
    const float s1v = s1[b * TT + arow];
    const int* adjp = adj + ((size_t)b * TT + arow) * TT;
    const unsigned short* hTb = hT + (size_t)b * FD * TT + (size_t)r15 * TT;
    const float* s2b = s2 + b * TT;

    f32x4 acc[8] = {};
    float lsum = 0.f;

    const int jbeg = w * (TT / 4);
    const int jend = jbeg + (TT / 4);

    for (int j0 = jbeg; j0 < jend; j0 += 64) {
        #pragma unroll
        for (int m = 0; m < 2; ++m) {
            const int koff = j0 + m * 32 + g * 8;
            int4 A0 = *reinterpret_cast<const int4*>(adjp + koff);
            int4 A1 = *reinterpret_cast<const int4*>(adjp + koff + 4);
            float4 S0 = *reinterpret_cast<const float4*>(s2b + koff);
            float4 S1 = *reinterpret_cast<const float4*>(s2b + koff + 4);
            int   ad[8] = {A0.x, A0.y, A0.z, A0.w, A1.x, A1.y, A1.z, A1.w};
            float sv[8] = {S0.x, S0.y, S0.z, S0.w, S1.x, S1.y, S1.z, S1.w};
            short8 af;
            #pragma unroll
            for (int e = 0; e < 8; ++e) {
                float s = s1v + sv[e];
                s = fmaxf(s, ALPHA * s);                     // leaky_relu
                float p = ad[e] ? __expf(s) : 0.f;           // mask -> exp(-1e9)=0
                unsigned short u = f2bf(p);
                af[e] = (short)u;
                lsum += bf2f(u);      // denominator from the SAME rounded weights
            }
            #pragma unroll
            for (int n = 0; n < 8; ++n) {
                short8 bfr = *reinterpret_cast<const short8*>(hTb + n * 16 * TT + koff);
                acc[n] = __builtin_amdgcn_mfma_f32_16x16x32_bf16(af, bfr, acc[n], 0, 0, 0);
            }
        }
    }

    // per-wave row sums (reduce over the 4 k-groups within the wave)
    lsum += __shfl_xor(lsum, 16);
    lsum += __shfl_xor(lsum, 32);
    if (g == 0) dsum[w][r15] = lsum;

    // two-step LDS reduction of the 4 wave-partial accumulators
    if (w < 2) {
        #pragma unroll
        for (int n = 0; n < 8; ++n)
            #pragma unroll
            for (int r = 0; r < 4; ++r)
                red[w][g * 4 + r][n * 16 + r15] = acc[n][r];
    }
    __syncthreads();
    if (w >= 2) {
        #pragma unroll
        for (int n = 0; n < 8; ++n)
            #pragma unroll
            for (int r = 0; r < 4; ++r)
                red[w - 2][g * 4 + r][n * 16 + r15] += acc[n][r];
    }
    __syncthreads();

    // epilogue: 16 rows x 128 cols = 512 float4s over 256 threads
    #pragma unroll
    for (int it = 0; it < 2; ++it) {
        int e = it * 256 + tid;
        int row = e >> 5;
        int c4 = (e & 31) << 2;
        float4 v0 = *reinterpret_cast<const float4*>(&red[0][row][c4]);
        float4 v1 = *reinterpret_cast<const float4*>(&red[1][row][c4]);
        float dn = dsum[0][row] + dsum[1][row] + dsum[2][row] + dsum[3][row];
        float ri = 1.0f / dn;
        float4 o;
        o.x = (v0.x + v1.x) * ri;
        o.y = (v0.y + v1.y) * ri;
        o.z = (v0.z + v1.z) * ri;
        o.w = (v0.w + v1.w) * ri;
        *reinterpret_cast<float4*>(out + ((size_t)(b * TT + i0 + row)) * FD + c4) = o;
    }
}

extern "C" void kernel_launch(void* const* d_in, const int* in_sizes, int n_in,
                              void* d_out, int out_size, void* d_ws, size_t ws_size,
                              hipStream_t stream)
{
    const float* x  = (const float*)d_in[0];
    const int* adj  = (const int*)d_in[1];
    const float* W  = (const float*)d_in[2];
    const float* a  = (const float*)d_in[3];
    float* out = (float*)d_out;

    unsigned short* hT = (unsigned short*)d_ws;                       // 8 MB bf16
    float* s1 = (float*)((char*)d_ws + (size_t)NB * FD * TT * 2);
    float* s2 = s1 + NB * TT;
    unsigned short* WT = (unsigned short*)(s2 + NB * TT);             // 32 KB bf16

    k_wt <<<16, 256, 0, stream>>>(W, WT);
    k_h  <<<NB * (TT / 64), 256, 0, stream>>>(x, WT, a, hT, s1, s2);
    k_att<<<NB * (TT / 16), 256, 0, stream>>>(adj, hT, s1, s2, out);
}

// Round 3
// 123.427 us; speedup vs baseline: 2.1949x; 1.7827x over previous
//
#include <hip/hip_runtime.h>

#define TT 2048
#define NB 16
#define FD 128
#define ALPHA 0.2f

typedef __attribute__((ext_vector_type(8))) short short8;
typedef __attribute__((ext_vector_type(4))) float f32x4;

static __device__ __forceinline__ unsigned short f2bf(float f) {
    unsigned u = __float_as_uint(f);
    u += 0x7FFF + ((u >> 16) & 1);          // round-to-nearest-even
    return (unsigned short)(u >> 16);
}
static __device__ __forceinline__ float bf2f(unsigned short s) {
    return __uint_as_float(((unsigned)s) << 16);
}

// Kernel 0: WT[f][k] = bf16(W[k][f])  (128x128, tiny)
__global__ __launch_bounds__(256) void k_wt(const float* __restrict__ W,
                                            unsigned short* __restrict__ WT)
{
    int fid = blockIdx.x * 256 + threadIdx.x;   // 4096 float4s
    int k = fid >> 5;
    int f = (fid & 31) << 2;
    float4 w4 = *reinterpret_cast<const float4*>(W + k * FD + f);
    WT[(f + 0) * FD + k] = f2bf(w4.x);
    WT[(f + 1) * FD + k] = f2bf(w4.y);
    WT[(f + 2) * FD + k] = f2bf(w4.z);
    WT[(f + 3) * FD + k] = f2bf(w4.w);
}

// Kernel 1: h = x@W (bf16 MFMA, WT from L2), write hT[b][f][t] bf16,
//           s1 = h@a1, s2 = h@a2 (fp32)
__global__ __launch_bounds__(256) void k_h(const float* __restrict__ x,
                                           const unsigned short* __restrict__ WT,
                                           const float* __restrict__ a,
                                           unsigned short* __restrict__ hT,
                                           float* __restrict__ s1,
                                           float* __restrict__ s2)
{
    __shared__ unsigned short hs[128][72];   // h-tile transpose staging

    const int tid = threadIdx.x;
    const int b  = blockIdx.x >> 5;
    const int t0 = (blockIdx.x & 31) << 6;
    const int w = tid >> 6, l = tid & 63, g = l >> 4, r15 = l & 15;

    const float* xrow = x + ((size_t)(b * TT + t0 + w * 16 + r15)) * FD;

    f32x4 acc[8] = {};

    #pragma unroll
    for (int m = 0; m < 4; ++m) {
        const int koff = m * 32 + g * 8;
        float4 xa = *reinterpret_cast<const float4*>(xrow + koff);
        float4 xb = *reinterpret_cast<const float4*>(xrow + koff + 4);
        short8 af;
        af[0] = (short)f2bf(xa.x); af[1] = (short)f2bf(xa.y);
        af[2] = (short)f2bf(xa.z); af[3] = (short)f2bf(xa.w);
        af[4] = (short)f2bf(xb.x); af[5] = (short)f2bf(xb.y);
        af[6] = (short)f2bf(xb.z); af[7] = (short)f2bf(xb.w);
        #pragma unroll
        for (int n = 0; n < 8; ++n) {
            short8 bfr = *reinterpret_cast<const short8*>(WT + (n * 16 + r15) * FD + koff);
            acc[n] = __builtin_amdgcn_mfma_f32_16x16x32_bf16(af, bfr, acc[n], 0, 0, 0);
        }
    }

    // s1/s2 from fp32 accumulators: lane holds h[t0+w*16+4g+r][16n+r15]
    float p1[4] = {0.f, 0.f, 0.f, 0.f}, p2[4] = {0.f, 0.f, 0.f, 0.f};
    #pragma unroll
    for (int n = 0; n < 8; ++n) {
        float a1v = a[n * 16 + r15];
        float a2v = a[FD + n * 16 + r15];
        #pragma unroll
        for (int r = 0; r < 4; ++r) {
            p1[r] += acc[n][r] * a1v;
            p2[r] += acc[n][r] * a2v;
        }
    }
    #pragma unroll
    for (int r = 0; r < 4; ++r) {
        #pragma unroll
        for (int off = 8; off >= 1; off >>= 1) {
            p1[r] += __shfl_xor(p1[r], off);
            p2[r] += __shfl_xor(p2[r], off);
        }
    }
    if (r15 == 0) {
        const int trow = t0 + w * 16 + g * 4;
        #pragma unroll
        for (int r = 0; r < 4; ++r) {
            s1[b * TT + trow + r] = p1[r];
            s2[b * TT + trow + r] = p2[r];
        }
    }

    // transpose h tile through LDS, write hT[b][f][t] coalesced
    #pragma unroll
    for (int n = 0; n < 8; ++n)
        #pragma unroll
        for (int r = 0; r < 4; ++r)
            hs[n * 16 + r15][w * 16 + g * 4 + r] = f2bf(acc[n][r]);
    __syncthreads();

    for (int i = tid; i < 1024; i += 256) {
        int f = i >> 3, c = i & 7;
        short8 v = *reinterpret_cast<const short8*>(&hs[f][c * 8]);
        *reinterpret_cast<short8*>(hT + ((size_t)(b * FD + f)) * TT + t0 + c * 8) = v;
    }
}

// Kernel 2: producer/consumer fused mask+softmax+PV.
// Block = 32 i-rows x full j, 4 waves split f (32 each). Per 128-j tile:
// producer (all threads) computes p bf16 -> LDS (double-buffered, adj
// register-prefetched one tile ahead); consumer MFMAs vs L2-resident hT.
// One raw s_barrier per tile (lgkmcnt drain only - adj loads stay in flight).
__global__ __launch_bounds__(256) void k_att(const int* __restrict__ adj,
                                             const unsigned short* __restrict__ hT,
                                             const float* __restrict__ s1,
                                             const float* __restrict__ s2,
                                             float* __restrict__ out)
{
    __shared__ __align__(16) unsigned short pbuf[2][32][136]; // 17x16B row stride
    __shared__ float dsum[32];

    const int tid = threadIdx.x;
    // bijective XCD swizzle: 1024 blocks = 8 XCDs x 128 contiguous
    const int wg = (blockIdx.x & 7) * 128 + (blockIdx.x >> 3);
    const int b  = wg >> 6;
    const int i0 = (wg & 63) << 5;
    const int w = tid >> 6, l = tid & 63, g = l >> 4, r15 = l & 15;

    // producer mapping: thread -> (row pr, 16-col group cg)
    const int pr = tid >> 3;
    const int cg = tid & 7;
    const int* adjp = adj + ((size_t)(b * TT + i0 + pr)) * TT + cg * 16;
    const float s1v = s1[b * TT + i0 + pr];
    const float* s2p = s2 + b * TT + cg * 16;
    unsigned short* prow = &pbuf[0][pr][cg * 16];

    // consumer mapping: wave w owns f-slice [w*32, w*32+32)
    const int f0 = w * 32;
    const unsigned short* hB0 = hT + (size_t)b * FD * TT + (size_t)(f0 + r15) * TT;
    const unsigned short* hB1 = hB0 + (size_t)(16 * TT);

    f32x4 acc00 = {}, acc01 = {}, acc10 = {}, acc11 = {};
    float rsum = 0.f;

    int4 arA[4], arB[4];
    #pragma unroll
    for (int q = 0; q < 4; ++q)
        arA[q] = *reinterpret_cast<const int4*>(adjp + q * 4);

    auto body = [&](int t, int4 (&cur)[4], int4 (&nxt)[4], const int bsel) {
        const int j0 = t * 128;
        if (t < 15) {                       // prefetch next adj tile
            #pragma unroll
            for (int q = 0; q < 4; ++q)
                nxt[q] = *reinterpret_cast<const int4*>(adjp + j0 + 128 + q * 4);
        }
        float4 s2v[4];
        #pragma unroll
        for (int q = 0; q < 4; ++q)
            s2v[q] = *reinterpret_cast<const float4*>(s2p + j0 + q * 4);
        short8 v0, v1;
        const int*   cai = (const int*)cur;
        const float* csf = (const float*)s2v;
        #pragma unroll
        for (int e = 0; e < 16; ++e) {
            float s = s1v + csf[e];
            s = fmaxf(s, ALPHA * s);                 // leaky_relu
            float p = cai[e] ? __expf(s) : 0.f;      // mask
            unsigned short u = f2bf(p);
            rsum += bf2f(u);                         // denom from rounded p
            if (e < 8) v0[e] = (short)u; else v1[e - 8] = (short)u;
        }
        unsigned short* dst = prow + bsel * (32 * 136);
        *reinterpret_cast<short8*>(dst)     = v0;
        *reinterpret_cast<short8*>(dst + 8) = v1;
        asm volatile("s_waitcnt lgkmcnt(0)" ::: "memory"); // LDS writes visible
        __builtin_amdgcn_s_barrier();                      // no vmcnt drain
        asm volatile("" ::: "memory");
        const unsigned short* pb = &pbuf[bsel][0][0];
        #pragma unroll
        for (int kk = 0; kk < 4; ++kk) {
            short8 A0 = *reinterpret_cast<const short8*>(pb + r15 * 136 + kk * 32 + g * 8);
            short8 A1 = *reinterpret_cast<const short8*>(pb + (16 + r15) * 136 + kk * 32 + g * 8);
            short8 B0 = *reinterpret_cast<const short8*>(hB0 + j0 + kk * 32 + g * 8);
            short8 B1 = *reinterpret_cast<const short8*>(hB1 + j0 + kk * 32 + g * 8);
            acc00 = __builtin_amdgcn_mfma_f32_16x16x32_bf16(A0, B0, acc00, 0, 0, 0);
            acc01 = __builtin_amdgcn_mfma_f32_16x16x32_bf16(A0, B1, acc01, 0, 0, 0);
            acc10 = __builtin_amdgcn_mfma_f32_16x16x32_bf16(A1, B0, acc10, 0, 0, 0);
            acc11 = __builtin_amdgcn_mfma_f32_16x16x32_bf16(A1, B1, acc11, 0, 0, 0);
        }
    };

    for (int tt = 0; tt < 8; ++tt) {
        body(2 * tt,     arA, arB, 0);
        body(2 * tt + 1, arB, arA, 1);
    }

    // row-sum reduce: 8 threads per row (same wave, lanes l&7)
    rsum += __shfl_xor(rsum, 1);
    rsum += __shfl_xor(rsum, 2);
    rsum += __shfl_xor(rsum, 4);
    if ((tid & 7) == 0) dsum[pr] = rsum;
    __syncthreads();

    float rinv0[4], rinv1[4];
    #pragma unroll
    for (int r = 0; r < 4; ++r) {
        rinv0[r] = 1.0f / dsum[g * 4 + r];
        rinv1[r] = 1.0f / dsum[16 + g * 4 + r];
    }
    const size_t obase = ((size_t)(b * TT + i0)) * FD + f0 + r15;
    #pragma unroll
    for (int r = 0; r < 4; ++r) {
        float* o0 = out + obase + (size_t)(g * 4 + r) * FD;
        float* o1 = out + obase + (size_t)(16 + g * 4 + r) * FD;
        o0[0]  = acc00[r] * rinv0[r];
        o0[16] = acc01[r] * rinv0[r];
        o1[0]  = acc10[r] * rinv1[r];
        o1[16] = acc11[r] * rinv1[r];
    }
}

extern "C" void kernel_launch(void* const* d_in, const int* in_sizes, int n_in,
                              void* d_out, int out_size, void* d_ws, size_t ws_size,
                              hipStream_t stream)
{
    const float* x  = (const float*)d_in[0];
    const int* adj  = (const int*)d_in[1];
    const float* W  = (const float*)d_in[2];
    const float* a  = (const float*)d_in[3];
    float* out = (float*)d_out;

    unsigned short* hT = (unsigned short*)d_ws;                       // 8 MB bf16
    float* s1 = (float*)((char*)d_ws + (size_t)NB * FD * TT * 2);
    float* s2 = s1 + NB * TT;
    unsigned short* WT = (unsigned short*)(s2 + NB * TT);             // 32 KB bf16

    k_wt <<<16, 256, 0, stream>>>(W, WT);
    k_h  <<<NB * (TT / 64), 256, 0, stream>>>(x, WT, a, hT, s1, s2);
    k_att<<<NB * (TT / 32), 256, 0, stream>>>(adj, hT, s1, s2, out);
}